// Round 2
// baseline (229.776 us; speedup 1.0000x reference)
//
#include <hip/hip_runtime.h>

// Hadamard on qubit TARGET=5 of N_QUBITS=24, batch=2, real float32 state.
// Per batch: L = 2^5 = 32, R = 2^18 floats (R4 = 2^16 float4).
// flat float4 index = bl * 2*R4 + r4 ; pair stride = R4 float4s.
// y0 = (x0 + x1) * inv_sqrt2 ; y1 = (x0 - x1) * inv_sqrt2.
//
// v3 vs v2 (v2 neutral: MLP x2 + nontemporal gained ~0):
//  - resident grid-stride: 2048 blocks (8/CU, fills the 32-wave/CU budget),
//    each thread loops over 8 float4-pairs. Tests the hypothesis that 8192
//    one-shot workgroups never reach streaming steady state (launch ramp /
//    drain + cold memory pipeline per workgroup).
//  - unroll 4: ~8 independent 16B loads in flight, ~60 VGPR (no occupancy
//    cliff at 4 waves/block x 8 blocks/CU).
//  - NT loads/stores kept from v2 (isolate the residency variable).

typedef float f4 __attribute__((ext_vector_type(4)));

__global__ __launch_bounds__(256) void hgate_kernel(const f4* __restrict__ x,
                                                    f4* __restrict__ y) {
    constexpr int R4_LOG2 = 16;                 // R/4 = 65536 float4
    constexpr int R4 = 1 << R4_LOG2;
    constexpr int TOTAL_PAIRS = 1 << 22;        // float4 pairs overall
    constexpr int NTHREADS = 2048 * 256;        // resident grid
    const float s = 0.70710678118654752440f;

    const int tid = blockIdx.x * blockDim.x + threadIdx.x;

#pragma unroll 4
    for (int t = tid; t < TOTAL_PAIRS; t += NTHREADS) {
        const int r4 = t & (R4 - 1);
        const int bl = t >> R4_LOG2;            // (batch, l) in [0, 64)
        const int idx0 = (bl << (R4_LOG2 + 1)) + r4;
        const int idx1 = idx0 + R4;

        f4 a = __builtin_nontemporal_load(x + idx0);
        f4 c = __builtin_nontemporal_load(x + idx1);

        f4 y0 = (a + c) * s;
        f4 y1 = (a - c) * s;

        __builtin_nontemporal_store(y0, y + idx0);
        __builtin_nontemporal_store(y1, y + idx1);
    }
}

extern "C" void kernel_launch(void* const* d_in, const int* in_sizes, int n_in,
                              void* d_out, int out_size, void* d_ws, size_t ws_size,
                              hipStream_t stream) {
    const f4* x = (const f4*)d_in[0];
    f4* y = (f4*)d_out;
    const int block = 256;
    const int grid = 2048;                      // 8 blocks/CU x 256 CUs
    hgate_kernel<<<grid, block, 0, stream>>>(x, y);
}

// Round 3
// 222.459 us; speedup vs baseline: 1.0329x; 1.0329x over previous
//
#include <hip/hip_runtime.h>

// Hadamard on qubit TARGET=5 of N_QUBITS=24, batch=2, real float32 state.
// Per batch: L = 2^5 = 32, R = 2^18 floats (R4 = 2^16 float4).
// flat float4 index = bl * 2*R4 + r4 ; pair stride = R4.
// y0 = (x0 + x1) * inv_sqrt2 ; y1 = (x0 - x1) * inv_sqrt2.
//
// v4 = revert to v2 (measured best, 220.4 us total).
// Session evidence: v1 (2 loads, plain) 221.8; v2 (4 loads, NT) 220.4;
// v3 (resident grid-stride, NT) 229.8. Total = 2x79.3us harness poison
// fills (write-ceiling-bound, fixed) + ~62us kernel. Kernel's effective
// ~4.3 TB/s vs 6.3 copy ceiling is attributed to the preceding fill's
// LLC write-back drain sharing HBM BW during the kernel's first ~38us
// (S3) — external to the kernel; MLP x2 / NT / residency all neutral or
// negative, consistent with that model.

typedef float f4 __attribute__((ext_vector_type(4)));

__global__ __launch_bounds__(256) void hgate_kernel(const f4* __restrict__ x,
                                                    f4* __restrict__ y) {
    constexpr int R4_LOG2 = 16;                // R/4 = 65536 float4
    constexpr int R4 = 1 << R4_LOG2;
    constexpr int HALF = 1 << 21;              // total threads; each does 2 pairs
    const float s = 0.70710678118654752440f;

    const int t = blockIdx.x * blockDim.x + threadIdx.x;   // [0, 2^21)
    const int u = t + HALF;                                // [2^21, 2^22)

    // idx = (bl << (R4_LOG2+1)) + r4 for each of the two work items
    const int a0 = ((t >> R4_LOG2) << (R4_LOG2 + 1)) + (t & (R4 - 1));
    const int b0 = ((u >> R4_LOG2) << (R4_LOG2 + 1)) + (u & (R4 - 1));
    const int a1 = a0 + R4;
    const int b1 = b0 + R4;

    // Issue all four loads before any dependent use.
    f4 xa0 = __builtin_nontemporal_load(x + a0);
    f4 xa1 = __builtin_nontemporal_load(x + a1);
    f4 xb0 = __builtin_nontemporal_load(x + b0);
    f4 xb1 = __builtin_nontemporal_load(x + b1);

    f4 ya0 = (xa0 + xa1) * s;
    f4 ya1 = (xa0 - xa1) * s;
    f4 yb0 = (xb0 + xb1) * s;
    f4 yb1 = (xb0 - xb1) * s;

    __builtin_nontemporal_store(ya0, y + a0);
    __builtin_nontemporal_store(ya1, y + a1);
    __builtin_nontemporal_store(yb0, y + b0);
    __builtin_nontemporal_store(yb1, y + b1);
}

extern "C" void kernel_launch(void* const* d_in, const int* in_sizes, int n_in,
                              void* d_out, int out_size, void* d_ws, size_t ws_size,
                              hipStream_t stream) {
    const f4* x = (const f4*)d_in[0];
    f4* y = (f4*)d_out;
    const int total_threads = 1 << 21;   // 2 float4-pairs per thread
    const int block = 256;
    const int grid = total_threads / block;   // 8192
    hgate_kernel<<<grid, block, 0, stream>>>(x, y);
}